// Round 1
// baseline (34.127 us; speedup 1.0000x reference)
//
#include <hip/hip_runtime.h>
#include <math.h>

namespace {
constexpr int P = 4096, O = 32, H = 26, V = 48;
constexpr float EPSV = 1e-4f;
}

// One thread per (point p, object o). Replicates numpy's op-for-op rounding:
// separate mul/add (no FMA contraction), sequential 3-term sums, IEEE div/sqrt.
__global__ __launch_bounds__(256) void zono_kernel(
    const float* __restrict__ point,   // [P][3]
    const float* __restrict__ hA,      // [O][H][3]
    const float* __restrict__ hb,      // [O][H]
    const float* __restrict__ v1g,     // [O][V][3]
    const float* __restrict__ v2g,     // [O][V][3]
    float* __restrict__ dist_out,      // [P][O]
    float* __restrict__ grad_out)      // [P][O][3]
{
    __shared__ float4 sAb[H];   // {a0,a1,a2,b}
    __shared__ float4 sV1[V];   // {v1_0,v1_1,v1_2,denom}
    __shared__ float4 sE[V];    // {e0,e1,e2,unused}

    const int o   = blockIdx.y;
    const int tid = threadIdx.x;

    if (tid < H) {
        const float* a = hA + (o * H + tid) * 3;
        sAb[tid] = make_float4(a[0], a[1], a[2], hb[o * H + tid]);
    } else if (tid >= 32 && tid < 32 + V) {
        const int v = tid - 32;
        const float* A1 = v1g + (o * V + v) * 3;
        const float* A2 = v2g + (o * V + v) * 3;
        const float x0 = A1[0], x1 = A1[1], x2 = A1[2];
        const float e0 = __fsub_rn(A2[0], x0);
        const float e1 = __fsub_rn(A2[1], x1);
        const float e2 = __fsub_rn(A2[2], x2);
        // denom = (e0*e0 + e1*e1) + e2*e2, numpy sequential order
        const float den = __fadd_rn(__fadd_rn(__fmul_rn(e0, e0), __fmul_rn(e1, e1)),
                                    __fmul_rn(e2, e2));
        sV1[v] = make_float4(x0, x1, x2, den);
        sE[v]  = make_float4(e0, e1, e2, 0.f);
    }
    __syncthreads();

    const int p = blockIdx.x * blockDim.x + tid;
    const float p0 = point[p * 3 + 0];
    const float p1 = point[p * 3 + 1];
    const float p2 = point[p * 3 + 2];

    // ---- face pass: s_h, is_neg, argmax, projection test, min perp ----
    bool  is_neg  = true;
    float maxv    = -INFINITY; int maxi = 0;
    float minperp =  INFINITY; int mini = 0;

    for (int h = 0; h < H; ++h) {
        const float4 ab = sAb[h];
        // s_h = ((p0*a0 + p1*a1) + p2*a2) - b
        const float sh = __fsub_rn(
            __fadd_rn(__fadd_rn(__fmul_rn(p0, ab.x), __fmul_rn(p1, ab.y)),
                      __fmul_rn(p2, ab.z)),
            ab.w);
        if (sh > 0.f) is_neg = false;
        if (sh > maxv) { maxv = sh; maxi = h; }   // strict > == first argmax

        // pp = p - s_h * a   (rounded exactly as numpy: mul then sub)
        const float pp0 = __fsub_rn(p0, __fmul_rn(sh, ab.x));
        const float pp1 = __fsub_rn(p1, __fmul_rn(sh, ab.y));
        const float pp2 = __fsub_rn(p2, __fmul_rn(sh, ab.z));

        bool onz = true;
        #pragma unroll
        for (int j = 0; j < H; ++j) {
            const float4 ab2 = sAb[j];
            const float t = __fsub_rn(
                __fadd_rn(__fadd_rn(__fmul_rn(pp0, ab2.x), __fmul_rn(pp1, ab2.y)),
                          __fmul_rn(pp2, ab2.z)),
                ab2.w);
            onz = onz && (t <= EPSV);
        }

        // perp = || p - pp ||  (numpy recomputes the difference)
        const float d0 = __fsub_rn(p0, pp0);
        const float d1 = __fsub_rn(p1, pp1);
        const float d2 = __fsub_rn(p2, pp2);
        float perp = __fsqrt_rn(
            __fadd_rn(__fadd_rn(__fmul_rn(d0, d0), __fmul_rn(d1, d1)),
                      __fmul_rn(d2, d2)));
        if (!onz) perp = INFINITY;
        if (perp < minperp) { minperp = perp; mini = h; }  // strict < == first argmin
    }

    // ---- edge pass: closest point on each segment ----
    float mine = INFINITY;
    float vm0 = 0.f, vm1 = 0.f, vm2 = 0.f;
    for (int v = 0; v < V; ++v) {
        const float4 V1 = sV1[v];
        const float4 E  = sE[v];
        const float w0 = __fsub_rn(p0, V1.x);
        const float w1 = __fsub_rn(p1, V1.y);
        const float w2 = __fsub_rn(p2, V1.z);
        const float th = __fdiv_rn(
            __fadd_rn(__fadd_rn(__fmul_rn(w0, E.x), __fmul_rn(w1, E.y)),
                      __fmul_rn(w2, E.z)),
            V1.w);
        const float ts = fminf(fmaxf(th, 0.f), 1.f);
        const float q0 = __fadd_rn(V1.x, __fmul_rn(ts, E.x));
        const float q1 = __fadd_rn(V1.y, __fmul_rn(ts, E.y));
        const float q2 = __fadd_rn(V1.z, __fmul_rn(ts, E.z));
        const float g0 = __fsub_rn(p0, q0);
        const float g1 = __fsub_rn(p1, q1);
        const float g2 = __fsub_rn(p2, q2);
        const float ed = __fsqrt_rn(
            __fadd_rn(__fadd_rn(__fmul_rn(g0, g0), __fmul_rn(g1, g1)),
                      __fmul_rn(g2, g2)));
        if (ed < mine) { mine = ed; vm0 = q0; vm1 = q1; vm2 = q2; }
    }

    // ---- select ----
    const int   fidx = is_neg ? maxi : mini;
    const float4 ga  = sAb[fidx];
    float dist = is_neg ? maxv : minperp;
    float g0 = ga.x, g1 = ga.y, g2 = ga.z;
    if (!is_neg && (mine < dist)) {
        dist = mine;
        g0 = __fdiv_rn(__fsub_rn(p0, vm0), mine);
        g1 = __fdiv_rn(__fsub_rn(p1, vm1), mine);
        g2 = __fdiv_rn(__fsub_rn(p2, vm2), mine);
    }

    const int idx = p * O + o;
    dist_out[idx] = dist;
    grad_out[idx * 3 + 0] = g0;
    grad_out[idx * 3 + 1] = g1;
    grad_out[idx * 3 + 2] = g2;
}

extern "C" void kernel_launch(void* const* d_in, const int* in_sizes, int n_in,
                              void* d_out, int out_size, void* d_ws, size_t ws_size,
                              hipStream_t stream) {
    const float* point = (const float*)d_in[0];
    const float* hA    = (const float*)d_in[1];
    const float* hb    = (const float*)d_in[2];
    const float* v1    = (const float*)d_in[3];
    const float* v2    = (const float*)d_in[4];
    float* out = (float*)d_out;

    dim3 grid(P / 256, O);
    zono_kernel<<<grid, dim3(256), 0, stream>>>(point, hA, hb, v1, v2,
                                                out, out + P * O);
}

// Round 2
// 28.444 us; speedup vs baseline: 1.1998x; 1.1998x over previous
//
#include <hip/hip_runtime.h>
#include <math.h>

namespace {
constexpr int P = 4096, O = 32, H = 26, V = 48;
constexpr float EPSV = 1e-4f;  // strict < EPSV matches numpy's (f32 <= 1e-4 f64) exactly
}

// One thread per (point p, object o). Replicates numpy's op-for-op rounding:
// separate mul/add (no FMA contraction), sequential 3-term sums, IEEE div/sqrt.
// A-matrix lives in per-thread VGPRs for the O(H^2) inner loop.
__global__ __launch_bounds__(256, 2) void zono_kernel(
    const float* __restrict__ point,   // [P][3]
    const float* __restrict__ hA,      // [O][H][3]
    const float* __restrict__ hb,      // [O][H]
    const float* __restrict__ v1g,     // [O][V][3]
    const float* __restrict__ v2g,     // [O][V][3]
    float* __restrict__ dist_out,      // [P][O]
    float* __restrict__ grad_out)      // [P][O][3]
{
    __shared__ float4 sAb[H];   // {a0,a1,a2,b}
    __shared__ float4 sV1[V];   // {v1_0,v1_1,v1_2,denom}
    __shared__ float4 sE[V];    // {e0,e1,e2,unused}

    const int o   = blockIdx.y;
    const int tid = threadIdx.x;

    if (tid < H) {
        const float* a = hA + (o * H + tid) * 3;
        sAb[tid] = make_float4(a[0], a[1], a[2], hb[o * H + tid]);
    } else if (tid >= 32 && tid < 32 + V) {
        const int v = tid - 32;
        const float* A1 = v1g + (o * V + v) * 3;
        const float* A2 = v2g + (o * V + v) * 3;
        const float x0 = A1[0], x1 = A1[1], x2 = A1[2];
        const float e0 = __fsub_rn(A2[0], x0);
        const float e1 = __fsub_rn(A2[1], x1);
        const float e2 = __fsub_rn(A2[2], x2);
        const float den = __fadd_rn(__fadd_rn(__fmul_rn(e0, e0), __fmul_rn(e1, e1)),
                                    __fmul_rn(e2, e2));
        sV1[v] = make_float4(x0, x1, x2, den);
        sE[v]  = make_float4(e0, e1, e2, 0.f);
    }
    __syncthreads();

    // Per-thread register copy of the face table (compile-time indexed only).
    float4 rA[H];
    #pragma unroll
    for (int j = 0; j < H; ++j) rA[j] = sAb[j];

    const int p = blockIdx.x * blockDim.x + tid;
    const float p0 = point[p * 3 + 0];
    const float p1 = point[p * 3 + 1];
    const float p2 = point[p * 3 + 2];

    // ---- face pass: s_h, is_neg, argmax, projection test, min perp ----
    bool  is_neg  = true;
    float maxv    = -INFINITY; int maxi = 0;
    float minperp =  INFINITY; int mini = 0;

    for (int h = 0; h < H; ++h) {
        const float4 ab = sAb[h];  // dynamic h -> LDS (keeps rA in registers)
        const float sh = __fsub_rn(
            __fadd_rn(__fadd_rn(__fmul_rn(p0, ab.x), __fmul_rn(p1, ab.y)),
                      __fmul_rn(p2, ab.z)),
            ab.w);
        if (sh > 0.f) is_neg = false;
        if (sh > maxv) { maxv = sh; maxi = h; }   // strict > == first argmax

        // pp = p - s_h * a   (mul then sub, numpy rounding)
        const float pp0 = __fsub_rn(p0, __fmul_rn(sh, ab.x));
        const float pp1 = __fsub_rn(p1, __fmul_rn(sh, ab.y));
        const float pp2 = __fsub_rn(p2, __fmul_rn(sh, ab.z));

        // onz = all_j (t_j < EPSV)  ==  max_j t_j < EPSV   (4-way fmax tree)
        float m0 = -INFINITY, m1 = -INFINITY, m2 = -INFINITY, m3 = -INFINITY;
        #pragma unroll
        for (int j = 0; j < H; j += 2) {
            const float4 qa = rA[j];
            const float ta = __fsub_rn(
                __fadd_rn(__fadd_rn(__fmul_rn(pp0, qa.x), __fmul_rn(pp1, qa.y)),
                          __fmul_rn(pp2, qa.z)),
                qa.w);
            m0 = fmaxf(m0, ta);
            if (j + 1 < H) {
                const float4 qb = rA[j + 1];
                const float tb = __fsub_rn(
                    __fadd_rn(__fadd_rn(__fmul_rn(pp0, qb.x), __fmul_rn(pp1, qb.y)),
                              __fmul_rn(pp2, qb.z)),
                    qb.w);
                m1 = fmaxf(m1, tb);
            }
        }
        const float tmax = fmaxf(fmaxf(m0, m1), fmaxf(m2, m3));
        const bool onz = (tmax < EPSV);

        // perp = || p - pp ||  (numpy recomputes the difference)
        const float d0 = __fsub_rn(p0, pp0);
        const float d1 = __fsub_rn(p1, pp1);
        const float d2 = __fsub_rn(p2, pp2);
        float perp = __fsqrt_rn(
            __fadd_rn(__fadd_rn(__fmul_rn(d0, d0), __fmul_rn(d1, d1)),
                      __fmul_rn(d2, d2)));
        if (!onz) perp = INFINITY;
        if (perp < minperp) { minperp = perp; mini = h; }  // strict < == first argmin
    }

    // ---- edge pass: closest point on each segment ----
    float mine = INFINITY;
    float vm0 = 0.f, vm1 = 0.f, vm2 = 0.f;
    #pragma unroll 2
    for (int v = 0; v < V; ++v) {
        const float4 V1 = sV1[v];
        const float4 E  = sE[v];
        const float w0 = __fsub_rn(p0, V1.x);
        const float w1 = __fsub_rn(p1, V1.y);
        const float w2 = __fsub_rn(p2, V1.z);
        const float th = __fdiv_rn(
            __fadd_rn(__fadd_rn(__fmul_rn(w0, E.x), __fmul_rn(w1, E.y)),
                      __fmul_rn(w2, E.z)),
            V1.w);
        const float ts = fminf(fmaxf(th, 0.f), 1.f);
        const float q0 = __fadd_rn(V1.x, __fmul_rn(ts, E.x));
        const float q1 = __fadd_rn(V1.y, __fmul_rn(ts, E.y));
        const float q2 = __fadd_rn(V1.z, __fmul_rn(ts, E.z));
        const float g0 = __fsub_rn(p0, q0);
        const float g1 = __fsub_rn(p1, q1);
        const float g2 = __fsub_rn(p2, q2);
        const float ed = __fsqrt_rn(
            __fadd_rn(__fadd_rn(__fmul_rn(g0, g0), __fmul_rn(g1, g1)),
                      __fmul_rn(g2, g2)));
        if (ed < mine) { mine = ed; vm0 = q0; vm1 = q1; vm2 = q2; }
    }

    // ---- select ----
    const int   fidx = is_neg ? maxi : mini;
    const float4 ga  = sAb[fidx];   // dynamic index -> LDS, one read
    float dist = is_neg ? maxv : minperp;
    float g0 = ga.x, g1 = ga.y, g2 = ga.z;
    if (!is_neg && (mine < dist)) {
        dist = mine;
        g0 = __fdiv_rn(__fsub_rn(p0, vm0), mine);
        g1 = __fdiv_rn(__fsub_rn(p1, vm1), mine);
        g2 = __fdiv_rn(__fsub_rn(p2, vm2), mine);
    }

    const int idx = p * O + o;
    dist_out[idx] = dist;
    grad_out[idx * 3 + 0] = g0;
    grad_out[idx * 3 + 1] = g1;
    grad_out[idx * 3 + 2] = g2;
}

extern "C" void kernel_launch(void* const* d_in, const int* in_sizes, int n_in,
                              void* d_out, int out_size, void* d_ws, size_t ws_size,
                              hipStream_t stream) {
    const float* point = (const float*)d_in[0];
    const float* hA    = (const float*)d_in[1];
    const float* hb    = (const float*)d_in[2];
    const float* v1    = (const float*)d_in[3];
    const float* v2    = (const float*)d_in[4];
    float* out = (float*)d_out;

    dim3 grid(P / 256, O);
    zono_kernel<<<grid, dim3(256), 0, stream>>>(point, hA, hb, v1, v2,
                                                out, out + P * O);
}